// Round 7
// baseline (61.338 us; speedup 1.0000x reference)
//
#include <hip/hip_runtime.h>

typedef __attribute__((ext_vector_type(8))) short short8;
typedef __attribute__((ext_vector_type(4))) short short4v;
typedef __attribute__((ext_vector_type(4))) float f32x4;
typedef __attribute__((ext_vector_type(16))) float f32x16;
typedef unsigned short ushort_t;

#define B_ 4
#define N_ 4096
#define E_ 256
#define D_ 64
#define KS_ 80                      // K global stride: 64 d + bias col + pad
#define KROW_ 88                    // K LDS row stride (elements)
#define S2LOG 0.1803368801111204f   // (1/sqrt(64)) * log2(e), folded into K at proj
#define BIGNEG (-1e30f)
#define THR 8.0f                    // defer-max threshold (log2 units)
#define ROWPAT(r) ((((r)&3)) + 8*((r)>>2))

static __device__ __forceinline__ unsigned short f2bf(float f) {
  union { float f; unsigned int u; } v; v.f = f;
  return (unsigned short)((v.u + 0x7fffu + ((v.u >> 16) & 1u)) >> 16);  // RNE
}
static __device__ __forceinline__ float bf2f(unsigned short h) {
  union { unsigned u; float f; } c; c.u = ((unsigned)h) << 16; return c.f;
}
static __device__ __forceinline__ float exp2_fast(float x) {
  float r; asm("v_exp_f32 %0, %1" : "=v"(r) : "v"(x)); return r;
}
static __device__ __forceinline__ unsigned cvt_pk_bf16(float lo, float hi) {
  unsigned r; asm("v_cvt_pk_bf16_f32 %0, %1, %2" : "=v"(r) : "v"(lo), "v"(hi));
  return r;
}

// ---------------------------------------------------------------------------
// Projection. p=0: q [B*N][64]; p=1: k' [B*N][80] = S2LOG*k with bias col 64
// (0 or -1e30 bf16, cols 65..79 = 0); p=2: vT [B][64][N].
// ---------------------------------------------------------------------------
__global__ __launch_bounds__(256) void proj_kernel(
    const float* __restrict__ Qv, const float* __restrict__ Kv,
    const float* __restrict__ Vv, const float* __restrict__ Wq,
    const float* __restrict__ Wk, const float* __restrict__ Wv,
    const int* __restrict__ mask,
    unsigned short* __restrict__ qo, unsigned short* __restrict__ ko,
    unsigned short* __restrict__ vto)
{
  const int p  = blockIdx.y;
  const int rb = blockIdx.x;
  const int t  = threadIdx.x;

  __align__(16) __shared__ unsigned short Xl[64 * 264];
  __align__(16) __shared__ unsigned short Wl[64 * 264];

  const float* xsrc = (p == 0 ? Qv : (p == 1 ? Kv : Vv)) + (size_t)rb * 64 * E_;
  const float* wsrc = (p == 0 ? Wq : (p == 1 ? Wk : Wv));

  #pragma unroll
  for (int it = 0; it < 8; ++it) {
    int idx = it * 2048 + t * 8;
    int row = idx >> 8, col = idx & 255;
    float4 a0 = *(const float4*)(xsrc + idx);
    float4 a1 = *(const float4*)(xsrc + idx + 4);
    uint4 wx;
    wx.x = (unsigned)f2bf(a0.x) | ((unsigned)f2bf(a0.y) << 16);
    wx.y = (unsigned)f2bf(a0.z) | ((unsigned)f2bf(a0.w) << 16);
    wx.z = (unsigned)f2bf(a1.x) | ((unsigned)f2bf(a1.y) << 16);
    wx.w = (unsigned)f2bf(a1.z) | ((unsigned)f2bf(a1.w) << 16);
    *(uint4*)&Xl[row * 264 + col] = wx;
    float4 b0 = *(const float4*)(wsrc + idx);
    float4 b1 = *(const float4*)(wsrc + idx + 4);
    uint4 ww;
    ww.x = (unsigned)f2bf(b0.x) | ((unsigned)f2bf(b0.y) << 16);
    ww.y = (unsigned)f2bf(b0.z) | ((unsigned)f2bf(b0.w) << 16);
    ww.z = (unsigned)f2bf(b1.x) | ((unsigned)f2bf(b1.y) << 16);
    ww.w = (unsigned)f2bf(b1.z) | ((unsigned)f2bf(b1.w) << 16);
    *(uint4*)&Wl[row * 264 + col] = ww;
  }
  // bias + zero-pad cols for K' (threads 0..255 cover 64 rows x 16 cols)
  if (p == 1) {
    int row = t >> 2, qd = (t & 3) * 4;
    int n = rb * 64 + row;
    ushort4 z; z.x = 0; z.y = 0; z.z = 0; z.w = 0;
    if (qd == 0) z.x = mask[n] ? (unsigned short)0 : f2bf(BIGNEG);
    *(ushort4*)&ko[(size_t)n * KS_ + 64 + qd] = z;
  }
  __syncthreads();

  const int wave = t >> 6, lane = t & 63, g = lane >> 4, lq = lane & 15;
  const unsigned short* TA = (p == 2) ? Wl : Xl;
  const unsigned short* TB = (p == 2) ? Xl : Wl;

  f32x4 acc0 = {0.f,0.f,0.f,0.f}, acc1 = acc0, acc2 = acc0, acc3 = acc0;
  #pragma unroll
  for (int kc = 0; kc < 8; ++kc) {
    short8 af = *(const short8*)&TA[(wave * 16 + lq) * 264 + kc * 32 + g * 8];
    short8 b0 = *(const short8*)&TB[(0 * 16 + lq) * 264 + kc * 32 + g * 8];
    acc0 = __builtin_amdgcn_mfma_f32_16x16x32_bf16(af, b0, acc0, 0, 0, 0);
    short8 b1 = *(const short8*)&TB[(1 * 16 + lq) * 264 + kc * 32 + g * 8];
    acc1 = __builtin_amdgcn_mfma_f32_16x16x32_bf16(af, b1, acc1, 0, 0, 0);
    short8 b2 = *(const short8*)&TB[(2 * 16 + lq) * 264 + kc * 32 + g * 8];
    acc2 = __builtin_amdgcn_mfma_f32_16x16x32_bf16(af, b2, acc2, 0, 0, 0);
    short8 b3 = *(const short8*)&TB[(3 * 16 + lq) * 264 + kc * 32 + g * 8];
    acc3 = __builtin_amdgcn_mfma_f32_16x16x32_bf16(af, b3, acc3, 0, 0, 0);
  }

  if (p < 2) {
    unsigned short* dst = (p == 0 ? qo : ko);
    const int stride = (p == 0 ? 64 : KS_);
    const float scl = (p == 0 ? 1.f : S2LOG);
    #pragma unroll
    for (int c = 0; c < 4; ++c) {
      const f32x4 ac = (c == 0 ? acc0 : c == 1 ? acc1 : c == 2 ? acc2 : acc3);
      #pragma unroll
      for (int r = 0; r < 4; ++r) {
        int n = rb * 64 + wave * 16 + g * 4 + r;
        dst[(size_t)n * stride + c * 16 + lq] = f2bf(ac[r] * scl);
      }
    }
  } else {
    int bb = (rb * 64) >> 12;
    #pragma unroll
    for (int c = 0; c < 4; ++c) {
      const f32x4 ac = (c == 0 ? acc0 : c == 1 ? acc1 : c == 2 ? acc2 : acc3);
      #pragma unroll
      for (int r = 0; r < 4; ++r) {
        int d = wave * 16 + g * 4 + r;
        int n = (rb * 64 + c * 16 + lq) & (N_ - 1);
        vto[((size_t)bb * D_ + d) * N_ + n] = f2bf(ac[r]);
      }
    }
  }
}

// ---------------------------------------------------------------------------
// vmean[b][d] = (1/N) sum_n v[b][n][d].  64 blocks x 4 waves, coalesced.
// ---------------------------------------------------------------------------
__global__ __launch_bounds__(256) void vmean_kernel(
    const ushort_t* __restrict__ vt, float* __restrict__ vmean)
{
  const int t = threadIdx.x, wave = t >> 6, lane = t & 63;
  const int idx = blockIdx.x * 4 + wave;
  const ushort_t* row = vt + (size_t)idx * N_;
  float s = 0.f;
  #pragma unroll
  for (int i = 0; i < 8; ++i) {
    short8 v = *(const short8*)&row[(i * 64 + lane) * 8];
    #pragma unroll
    for (int j = 0; j < 8; ++j) s += bf2f((unsigned short)v[j]);
  }
  #pragma unroll
  for (int off = 1; off < 64; off <<= 1) s += __shfl_xor(s, off, 64);
  if (lane == 0) vmean[idx] = s * (1.f / N_);
}

// ---------------------------------------------------------------------------
// Flash attention, KV-split, 32x32x16 MFMA. 8 waves x 32 q = 256 q/block;
// key tile 64 (processed as 2x32 blocks); mask/scale folded into K' (d=64
// bias column); P stays in registers (key-permuted A-frag, V read as 2x b64
// per MFMA compensates); double-buffered LDS, 1 barrier/tile.
// LDS = 38.9 KB; launch_bounds(512,4) caps VGPR at 128 (est. ~110 live).
// ---------------------------------------------------------------------------
__global__ __launch_bounds__(512, 4) void attn7_kernel(
    const ushort_t* __restrict__ q, const ushort_t* __restrict__ kk,
    const ushort_t* __restrict__ vt,
    float* __restrict__ op0, float* __restrict__ opws,
    float* __restrict__ mlbuf, int nsplit)
{
  const int b = blockIdx.y, qt = blockIdx.x, sp = blockIdx.z;
  const int t = threadIdx.x;
  const int wave = t >> 6, lane = t & 63;
  const int l31 = lane & 31, hi = lane >> 5;

  const int TT = N_ / 64;
  const int tile_lo = (sp * TT) / nsplit;
  const int tile_hi = ((sp + 1) * TT) / nsplit;
  const int nit = tile_hi - tile_lo;

  __align__(16) __shared__ ushort_t Kt[2][64 * KROW_];  // [key][88], chunk-XOR swz
  __align__(16) __shared__ ushort_t Vt[2][64 * 64];     // [d][key], chunk-XOR swz

  const int qw = qt * 256 + wave * 32;    // wave's first q (within batch)
  const size_t qrow = (size_t)(b * N_ + qw + l31) * D_;
  short8 qr0 = *(const short8*)&q[qrow + 0  + 8 * hi];
  short8 qr1 = *(const short8*)&q[qrow + 16 + 8 * hi];
  short8 qr2 = *(const short8*)&q[qrow + 32 + 8 * hi];
  short8 qr3 = *(const short8*)&q[qrow + 48 + 8 * hi];
  short8 qc4 = {0,0,0,0,0,0,0,0};         // bias-dim Q': 1.0 at d=64, else 0
  if (hi == 0) qc4[0] = (short)0x3F80;

  float m = 0.f, lsum = 0.f;              // finite m init; defer-max bounds p<=2^THR
  f32x16 o0, o1;                          // O' accum: row q=ROWPAT(r)+4hi, col d
  #pragma unroll
  for (int r = 0; r < 16; ++r) { o0[r] = 0.f; o1[r] = 0.f; }

  const int sr = t >> 3, sc = t & 7;      // staging coords
  uint4 kr0, vr0, kr1;

  auto stage_load = [&](int tile) {
    const int jb = (tile_lo + tile) * 64;
    kr0 = *(const uint4*)&kk[(size_t)(b * N_ + jb + sr) * KS_ + sc * 8];
    vr0 = *(const uint4*)&vt[((size_t)b * D_ + sr) * N_ + jb + sc * 8];
    if (t < 128)
      kr1 = *(const uint4*)&kk[(size_t)(b * N_ + jb + ((t >> 1) & 63)) * KS_ + 64 + (t & 1) * 8];
  };
  auto stage_write = [&](int bufi) {
    *(uint4*)&Kt[bufi][sr * KROW_ + ((sc ^ (sr & 7)) * 8)] = kr0;
    *(uint4*)&Vt[bufi][sr * 64 + ((sc ^ (sr & 7)) * 8)] = vr0;
    if (t < 128)
      *(uint4*)&Kt[bufi][((t >> 1) & 63) * KROW_ + (8 + (t & 1)) * 8] = kr1;
  };

  stage_load(0);
  stage_write(0);
  __syncthreads();

  for (int it = 0; it < nit; ++it) {
    const int bufi = it & 1;
    const int jb = (tile_lo + it) * 64;
    const bool more = (it + 1 < nit);
    if (more) stage_load(it + 1);        // VMEM in flight across compute

    const bool isdiag = (jb == (qw & ~63));
    const int qkb = (qw >> 5) & 1;

    #pragma unroll
    for (int kb = 0; kb < 2; ++kb) {
      // ---- QK^T: C[key][q], k-dim = 80 (incl bias col) ----
      const int krow = kb * 32 + l31, swz = krow & 7;
      const ushort_t* Kb = &Kt[bufi][krow * KROW_];
      f32x16 st;
      #pragma unroll
      for (int r = 0; r < 16; ++r) st[r] = 0.f;
      __builtin_amdgcn_s_setprio(1);
      {
        short8 ka;
        ka = *(const short8*)&Kb[((0 + hi) ^ swz) * 8];
        st = __builtin_amdgcn_mfma_f32_32x32x16_bf16(ka, qr0, st, 0, 0, 0);
        ka = *(const short8*)&Kb[((2 + hi) ^ swz) * 8];
        st = __builtin_amdgcn_mfma_f32_32x32x16_bf16(ka, qr1, st, 0, 0, 0);
        ka = *(const short8*)&Kb[((4 + hi) ^ swz) * 8];
        st = __builtin_amdgcn_mfma_f32_32x32x16_bf16(ka, qr2, st, 0, 0, 0);
        ka = *(const short8*)&Kb[((6 + hi) ^ swz) * 8];
        st = __builtin_amdgcn_mfma_f32_32x32x16_bf16(ka, qr3, st, 0, 0, 0);
        ka = *(const short8*)&Kb[(8 + hi) * 8];
        st = __builtin_amdgcn_mfma_f32_32x32x16_bf16(ka, qc4, st, 0, 0, 0);
      }
      __builtin_amdgcn_s_setprio(0);

      // ---- row max over this 32-key block (lane holds q=l31, 16 keys) ----
      float t0 = fmaxf(fmaxf(st[0], st[1]), fmaxf(st[2], st[3]));
      float t1 = fmaxf(fmaxf(st[4], st[5]), fmaxf(st[6], st[7]));
      float t2 = fmaxf(fmaxf(st[8], st[9]), fmaxf(st[10], st[11]));
      float t3 = fmaxf(fmaxf(st[12], st[13]), fmaxf(st[14], st[15]));
      float tm = fmaxf(fmaxf(t0, t1), fmaxf(t2, t3));
      tm = fmaxf(tm, __shfl_xor(tm, 32, 64));

      // ---- defer-max rescale (rare; wave-uniform trigger) ----
      if (!__all(tm - m <= THR)) {
        const float mnew = fmaxf(m, tm);
        const float corr = exp2_fast(m - mnew);
        #pragma unroll
        for (int r = 0; r < 16; ++r) {
          float c = __shfl(corr, ROWPAT(r) + 4 * hi, 64);
          o0[r] *= c; o1[r] *= c;
        }
        lsum *= corr;
        m = mnew;
      }

      // ---- P = exp2(st - m) in place; masked keys underflow to 0 ----
      #pragma unroll
      for (int r = 0; r < 16; ++r) st[r] = exp2_fast(st[r] - m);

      if (isdiag && kb == qkb) {         // diagonal exclusion (one tile/block)
        const int dloc = l31 - 4 * hi;
        #pragma unroll
        for (int r = 0; r < 16; ++r)
          st[r] = (ROWPAT(r) == dloc) ? 0.f : st[r];
      }

      // ---- l partial sum (f32) ----
      float s0 = ((st[0] + st[1]) + (st[2] + st[3])) + ((st[4] + st[5]) + (st[6] + st[7]));
      float s1 = ((st[8] + st[9]) + (st[10] + st[11])) + ((st[12] + st[13]) + (st[14] + st[15]));
      lsum += s0 + s1;

      // ---- pack P to bf16 A-frags (key-permuted: natural reg order!) ----
      union { unsigned u[4]; short8 s; } A0, A1;
      A0.u[0] = cvt_pk_bf16(st[0],  st[1]);
      A0.u[1] = cvt_pk_bf16(st[2],  st[3]);
      A0.u[2] = cvt_pk_bf16(st[4],  st[5]);
      A0.u[3] = cvt_pk_bf16(st[6],  st[7]);
      A1.u[0] = cvt_pk_bf16(st[8],  st[9]);
      A1.u[1] = cvt_pk_bf16(st[10], st[11]);
      A1.u[2] = cvt_pk_bf16(st[12], st[13]);
      A1.u[3] = cvt_pk_bf16(st[14], st[15]);

      // ---- PV: B = V with matching key permutation (2x b64 per MFMA) ----
      __builtin_amdgcn_s_setprio(1);
      #pragma unroll
      for (int db = 0; db < 2; ++db) {
        f32x16& oc = db ? o1 : o0;
        const ushort_t* Vb = &Vt[bufi][(db * 32 + l31) * 64];
        const int vsw = l31 & 7;
        short4v lo0 = *(const short4v*)&Vb[(((kb * 4 + 0) ^ vsw) * 8) + 4 * hi];
        short4v hi0 = *(const short4v*)&Vb[(((kb * 4 + 1) ^ vsw) * 8) + 4 * hi];
        short8 vb0 = __builtin_shufflevector(lo0, hi0, 0, 1, 2, 3, 4, 5, 6, 7);
        oc = __builtin_amdgcn_mfma_f32_32x32x16_bf16(A0.s, vb0, oc, 0, 0, 0);
        short4v lo1 = *(const short4v*)&Vb[(((kb * 4 + 2) ^ vsw) * 8) + 4 * hi];
        short4v hi1 = *(const short4v*)&Vb[(((kb * 4 + 3) ^ vsw) * 8) + 4 * hi];
        short8 vb1 = __builtin_shufflevector(lo1, hi1, 0, 1, 2, 3, 4, 5, 6, 7);
        oc = __builtin_amdgcn_mfma_f32_32x32x16_bf16(A1.s, vb1, oc, 0, 0, 0);
      }
      __builtin_amdgcn_s_setprio(0);
    }

    if (more) stage_write(bufi ^ 1);     // safe: all waves past prev-iter barrier
    __syncthreads();
  }

  // ---- epilogue: unnormalized O' + (m, l) ----
  float* obase = (sp == 0 ? op0 : opws + (size_t)(sp - 1) * (B_ * N_) * D_)
               + ((size_t)(b * N_) + qw) * D_ + l31;
  #pragma unroll
  for (int r = 0; r < 16; ++r) {
    obase[(size_t)(ROWPAT(r) + 4 * hi) * D_]      = o0[r];
    obase[(size_t)(ROWPAT(r) + 4 * hi) * D_ + 32] = o1[r];
  }
  float lt = lsum + __shfl_xor(lsum, 32, 64);
  if (lane < 32) {
    float* mlb = mlbuf + ((size_t)sp * (B_ * N_) + b * N_ + qw + lane) * 2;
    mlb[0] = m; mlb[1] = lt;
  }
}

// ---------------------------------------------------------------------------
// Merge splits; dead q-rows get the reference's uniform mean over all V.
// ---------------------------------------------------------------------------
__global__ __launch_bounds__(256) void merge_kernel(
    const float* __restrict__ op0, const float* __restrict__ opws,
    const float* __restrict__ mlbuf, const int* __restrict__ mask,
    const float* __restrict__ vmean, float* __restrict__ out, int nsplit)
{
  const int t = threadIdx.x;
  const int qrow = blockIdx.x * 16 + (t >> 4);
  const int d = (t & 15) * 4;
  const int b = qrow >> 12;

  if (!mask[qrow]) {
    *(float4*)&out[(size_t)qrow * D_ + d] = *(const float4*)&vmean[b * D_ + d];
    return;
  }

  float M = -INFINITY;
  for (int s = 0; s < nsplit; ++s)
    M = fmaxf(M, mlbuf[((size_t)s * (B_ * N_) + qrow) * 2]);

  float L = 0.f;
  float ax = 0.f, ay = 0.f, az = 0.f, aw = 0.f;
  for (int s = 0; s < nsplit; ++s) {
    const float* mlp = &mlbuf[((size_t)s * (B_ * N_) + qrow) * 2];
    const float w = exp2_fast(mlp[0] - M);
    L += mlp[1] * w;
    const float* ob = (s == 0) ? op0 : opws + (size_t)(s - 1) * (B_ * N_) * D_;
    float4 ov = *(const float4*)&ob[(size_t)qrow * D_ + d];
    ax += ov.x * w; ay += ov.y * w; az += ov.z * w; aw += ov.w * w;
  }
  const float inv = 1.f / L;
  float4 res; res.x = ax * inv; res.y = ay * inv; res.z = az * inv; res.w = aw * inv;
  *(float4*)&out[(size_t)qrow * D_ + d] = res;
}

// ---------------------------------------------------------------------------
extern "C" void kernel_launch(void* const* d_in, const int* in_sizes, int n_in,
                              void* d_out, int out_size, void* d_ws, size_t ws_size,
                              hipStream_t stream) {
  (void)in_sizes; (void)n_in; (void)out_size;
  const float* Qv = (const float*)d_in[0];
  const float* Kv = (const float*)d_in[1];
  const float* Vv = (const float*)d_in[2];
  const int* mask = (const int*)d_in[3];
  const float* Wq = (const float*)d_in[4];
  const float* Wk = (const float*)d_in[5];
  const float* Wv = (const float*)d_in[6];
  float* out = (float*)d_out;

  ushort_t* qb_ = (ushort_t*)d_ws;                         // [B*N][64] bf16
  ushort_t* kb_ = qb_ + (size_t)B_ * N_ * D_;              // [B*N][80] bf16 (K' + bias)
  ushort_t* vtb = kb_ + (size_t)B_ * N_ * KS_;             // [B][64][N] bf16
  float* vmean  = (float*)(vtb + (size_t)B_ * N_ * D_);    // [B][64] f32
  float* mlbuf  = vmean + (size_t)B_ * D_;                 // [8][B*N][2] f32 max
  float* opws   = mlbuf + (size_t)8 * B_ * N_ * 2;         // (nsplit-1) x [B*N][64] f32
  const size_t fixed_bytes = (size_t)((char*)opws - (char*)d_ws);
  const size_t slice_bytes = (size_t)B_ * N_ * D_ * sizeof(float);

  int nsplit = 1;
  if      (ws_size >= fixed_bytes + 7 * slice_bytes) nsplit = 8;
  else if (ws_size >= fixed_bytes + 3 * slice_bytes) nsplit = 4;
  else if (ws_size >= fixed_bytes + 1 * slice_bytes) nsplit = 2;

  proj_kernel<<<dim3(256, 3), dim3(256), 0, stream>>>(
      Qv, Kv, Vv, Wq, Wk, Wv, mask, qb_, kb_, vtb);
  vmean_kernel<<<dim3(64), dim3(256), 0, stream>>>(vtb, vmean);
  attn7_kernel<<<dim3(N_ / 256, B_, nsplit), dim3(512), 0, stream>>>(
      qb_, kb_, vtb, out, opws, mlbuf, nsplit);
  merge_kernel<<<dim3(B_ * N_ / 16), dim3(256), 0, stream>>>(
      out, opws, mlbuf, mask, vmean, out, nsplit);
}